// Round 7
// baseline (172.448 us; speedup 1.0000x reference)
//
#include <hip/hip_runtime.h>

#define CAR 8
#define SROW 520   // CAR + 64*CAR
#define HID 256
#define EOUT 257
#define XPAD 288   // padded Q-input row: 8 self + 257 enc + pad, 9 k-steps of 32
#define ADIM 30

typedef __attribute__((ext_vector_type(8))) short sh8;
typedef __attribute__((ext_vector_type(4))) float f32x4;

__device__ __forceinline__ short f2bf(float f) {
  unsigned u = __builtin_bit_cast(unsigned, f);
  u += 0x7fffu + ((u >> 16) & 1u);   // RNE
  return (short)(u >> 16);
}
// pack two fp32 -> packed bf16x2 (RNE, 5 VALU)
__device__ __forceinline__ unsigned f2bf2(float a, float b) {
  unsigned ua = __builtin_bit_cast(unsigned, a);
  ua += 0x7fffu + ((ua >> 16) & 1u);
  unsigned ub = __builtin_bit_cast(unsigned, b);
  ub += 0x7fffu + ((ub >> 16) & 1u);
  return __builtin_amdgcn_perm(ub, ua, 0x07060302);  // [a | b<<16]
}
// pack two fp32 -> packed bf16x2 (TRUNC, 1 VALU) — used for h staging only
__device__ __forceinline__ unsigned pkt(float a, float b) {
  return __builtin_amdgcn_perm(__builtin_bit_cast(unsigned, b),
                               __builtin_bit_cast(unsigned, a), 0x07060302);
}

// ---------------------------------------------------------------------------
// Prep: swizzle all weights to bf16 MFMA fragments. (R2-verbatim, verified)
// w1f : [W1;b1]^T as A [16 mt][64][8]  k=0..7 -> W1 row, k=8 -> b1   (8192)
// w2f : W2  as B   [8 ks][17 nt][64][8]               (69632)  stride/ks = 8704!
// w3f : Qw1 as B   [9 ks][16 nt][64][8], k=X-row idx  (73728)
// wq2f: Qw2 as B   [8 ks][2 nt][64][8]                (8192)
// ---------------------------------------------------------------------------
__global__ void k_prep(const float* __restrict__ W1, const float* __restrict__ b1,
                       const float* __restrict__ W2,
                       const float* __restrict__ Qw1, const float* __restrict__ Qw2,
                       short* __restrict__ w1f, short* __restrict__ w2f,
                       short* __restrict__ w3f, short* __restrict__ wq2f) {
  int idx = blockIdx.x * 256 + threadIdx.x;
  if (idx < 8192) {                         // [W1;b1]^T as A
    int mt = idx >> 9, r = idx & 511, lane = r >> 3, j = r & 7;
    int quad = lane >> 4, m = lane & 15;
    int hid = mt * 16 + m;
    float v = (quad == 0) ? W1[j * HID + hid]
            : (quad == 1 && j == 0) ? b1[hid] : 0.0f;   // k=8 row = b1
    w1f[idx] = f2bf(v);
    return;
  }
  int i2 = idx - 8192;
  if (i2 < 69632) {                         // W2 as B (ks stride = 17*512 = 8704)
    int ks = i2 / 8704, r = i2 % 8704;
    int nt = r >> 9, r2 = r & 511, lane = r2 >> 3, j = r2 & 7;
    int quad = lane >> 4, m = lane & 15;
    int k = ks * 32 + quad * 8 + j, n = nt * 16 + m;
    float v = (n < EOUT) ? W2[k * EOUT + n] : 0.0f;
    w2f[i2] = f2bf(v);
    return;
  }
  int i3 = i2 - 69632;
  if (i3 < 73728) {                         // Qw1 as B (k indexes padded X row)
    int ks = i3 >> 13, r = i3 & 8191;
    int nt = r >> 9, r2 = r & 511, lane = r2 >> 3, j = r2 & 7;
    int quad = lane >> 4, m = lane & 15;
    int k = ks * 32 + quad * 8 + j, n = nt * 16 + m;
    float v = (k < 265) ? Qw1[k * HID + n] : 0.0f;
    w3f[i3] = f2bf(v);
    return;
  }
  int i4 = i3 - 73728;
  if (i4 < 8192) {                          // Qw2 as B
    int ks = i4 >> 10, r = i4 & 1023;
    int nt = r >> 9, r2 = r & 511, lane = r2 >> 3, j = r2 & 7;
    int quad = lane >> 4, m = lane & 15;
    int k = ks * 32 + quad * 8 + j, n = nt * 16 + m;
    float v = (n < ADIM) ? Qw2[k * ADIM + n] : 0.0f;
    wq2f[i4] = f2bf(v);
  }
}

// ---------------------------------------------------------------------------
// K1: fused encoder + pool. NB=2 elems, 8 waves (512 thr). R6 base minus
// setprio, restructured as a K-split software pipeline to overlap the
// pipe-monochrome phases (measured: MfmaUtil 37 + VALUBusy 50, sum ~88%,
// phases serialize):
//   phase1a: stage h[hid 0..127] -> hldsA            (VALU+16x16 MFMA)
//   barrier
//   phase1b: stage h[hid 128..255] -> hldsB          } one scheduling region,
//   phase2a: acc += A(hldsA) @ B(ks 0..3)            } provably disjoint LDS
//   barrier
//   phase2b: acc += A(hldsB) @ B(ks 4..7) + epilogue
// Separate __shared__ arrays make phase1b/phase2a independence visible to
// the scheduler -> staging VALU hides under MFMA. Keeps bias-as-C-init and
// A16-dedup (both verified R6).
// ---------------------------------------------------------------------------
__global__ __launch_bounds__(512, 4)
void k_enc(const float* __restrict__ s, const short* __restrict__ w1f,
           const short* __restrict__ w2f, const float* __restrict__ b2,
           float* __restrict__ so288, int B) {
  __shared__ __align__(16) short hldsA[2][8192];  // 32 KB: [e][((g*4+ks)*64+slot)*8+j]
  __shared__ __align__(16) short hldsB[2][8192];  // 32 KB: ks' = ks-4
  __shared__ float ninvp[8];
  __shared__ float t16[8][16];

  const int tid = threadIdx.x;
  const int w = tid >> 6, lane = tid & 63;
  const int q = lane >> 4, m = lane & 15;
  const int we = w >> 2, g = w & 3;
  const size_t bg0 = 2 * (size_t)blockIdx.x;
  size_t bg = bg0 + we; if (bg >= (size_t)B) bg = B - 1;

  // ---- phase 1 input: 16 agents (group g) of elem we ----
  const float* srow0 = s + bg * SROW + CAR;
  int4 pk = {0, 0, 0, 0};
  bool inv = false;
  if (lane < 16) {                           // agent = 16*g + lane
    const float* sr = srow0 + (g * 16 + lane) * CAR;
    float4 f0 = ((const float4*)sr)[0], f1 = ((const float4*)sr)[1];
    inv = (f0.x == -1.f) | (f0.y == -1.f) | (f0.z == -1.f) | (f0.w == -1.f) |
          (f1.x == -1.f) | (f1.y == -1.f) | (f1.z == -1.f) | (f1.w == -1.f);
    if (!inv) {                              // mask folded at source
      pk.x = (int)f2bf2(f0.x, f0.y); pk.y = (int)f2bf2(f0.z, f0.w);
      pk.z = (int)f2bf2(f1.x, f1.y); pk.w = (int)f2bf2(f1.z, f1.w);
    }
  }
  const float vflag = inv ? 0.f : 1.f;
  unsigned long long bal = __ballot(inv);
  if (lane == 0) ninvp[w] = (float)__popcll(bal);

  if (w == 1 || w == 2) {                    // self-state + tail pad per elem
    size_t rr = bg0 + (w - 1); if (rr >= (size_t)B) rr = B - 1;
    if (lane < CAR)       so288[rr * XPAD + lane] = s[rr * SROW + lane];
    else if (lane < 16)   so288[rr * XPAD + 280 + (lane - 8)] = 0.f;
  }

  int4 p0;
  p0.x = __shfl(pk.x, m, 64); p0.y = __shfl(pk.y, m, 64);
  p0.z = __shfl(pk.z, m, 64); p0.w = __shfl(pk.w, m, 64);
  const float vv0 = __shfl(vflag, m, 64);
  if (q == 1) {                              // k=8 constant-1 column (masked)
    p0.x = (vv0 != 0.f) ? 0x3f80 : 0; p0.y = p0.z = p0.w = 0;
  } else if (q >= 2) {
    p0.x = p0.y = p0.z = p0.w = 0;
  }
  sh8 bs = __builtin_bit_cast(sh8, p0);

  // ---- phase 1a: hid 0..127 -> hldsA ----
#pragma unroll 4
  for (int mt = 0; mt < 8; ++mt) {
    sh8 af = *(const sh8*)(w1f + (mt * 64 + lane) * 8);
    f32x4 z = {0.f, 0.f, 0.f, 0.f};
    f32x4 c0 = __builtin_amdgcn_mfma_f32_16x16x32_bf16(af, bs, z, 0, 0, 0);
    const int hidb = mt * 16 + q * 4;
    const int ks = hidb >> 5, qB = (hidb >> 3) & 3, js = hidb & 7;
    uint2 k0;
    k0.x = pkt(fmaxf(c0[0], 0.f), fmaxf(c0[1], 0.f));
    k0.y = pkt(fmaxf(c0[2], 0.f), fmaxf(c0[3], 0.f));
    *(uint2*)(&hldsA[we][((g * 4 + ks) * 64 + qB * 16 + m) * 8 + js]) = k0;
  }
  __syncthreads();

  // acc init (bias as C-operand, verified R6)
  const int t0 = 2 * w;
  const float bi0  = b2[t0 * 16 + m];
  const float bi1  = b2[t0 * 16 + 16 + m];
  const float bi16 = (m == 0) ? b2[256] : 0.f;
  f32x4 acc[4][2][2];                        // [mtA][i][e]
  f32x4 acc16 = {bi16, bi16, bi16, bi16};
#pragma unroll
  for (int mtA = 0; mtA < 4; ++mtA)
#pragma unroll
    for (int e = 0; e < 2; ++e) {
      f32x4 c0 = {bi0, bi0, bi0, bi0};
      f32x4 c1 = {bi1, bi1, bi1, bi1};
      acc[mtA][0][e] = c0;
      acc[mtA][1][e] = c1;
    }

  // ---- phase 1b (stage hid 128..255 -> hldsB)  ||  phase 2a (ks 0..3) ----
  // Disjoint shared arrays -> scheduler may interleave freely.
#pragma unroll 4
  for (int mt = 8; mt < 16; ++mt) {
    sh8 af = *(const sh8*)(w1f + (mt * 64 + lane) * 8);
    f32x4 z = {0.f, 0.f, 0.f, 0.f};
    f32x4 c0 = __builtin_amdgcn_mfma_f32_16x16x32_bf16(af, bs, z, 0, 0, 0);
    const int hidb = mt * 16 + q * 4;
    const int ks2 = (hidb >> 5) - 4, qB = (hidb >> 3) & 3, js = hidb & 7;
    uint2 k0;
    k0.x = pkt(fmaxf(c0[0], 0.f), fmaxf(c0[1], 0.f));
    k0.y = pkt(fmaxf(c0[2], 0.f), fmaxf(c0[3], 0.f));
    *(uint2*)(&hldsB[we][((g * 4 + ks2) * 64 + qB * 16 + m) * 8 + js]) = k0;
  }
#pragma unroll
  for (int ks = 0; ks < 4; ++ks) {
    sh8 B0  = *(const sh8*)(w2f + ((ks * 17 + t0)     * 64 + lane) * 8);
    sh8 B1  = *(const sh8*)(w2f + ((ks * 17 + t0 + 1) * 64 + lane) * 8);
    sh8 B16 = *(const sh8*)(w2f + ((ks * 17 + 16)     * 64 + lane) * 8);
#pragma unroll
    for (int e = 0; e < 2; ++e) {
      sh8 A0 = *(const sh8*)(&hldsA[e][((0 * 4 + ks) * 64 + lane) * 8]);
      sh8 A1 = *(const sh8*)(&hldsA[e][((1 * 4 + ks) * 64 + lane) * 8]);
      sh8 A2 = *(const sh8*)(&hldsA[e][((2 * 4 + ks) * 64 + lane) * 8]);
      sh8 A3 = *(const sh8*)(&hldsA[e][((3 * 4 + ks) * 64 + lane) * 8]);
      acc[0][0][e] = __builtin_amdgcn_mfma_f32_16x16x32_bf16(A0, B0, acc[0][0][e], 0, 0, 0);
      acc[1][0][e] = __builtin_amdgcn_mfma_f32_16x16x32_bf16(A1, B0, acc[1][0][e], 0, 0, 0);
      acc[2][0][e] = __builtin_amdgcn_mfma_f32_16x16x32_bf16(A2, B0, acc[2][0][e], 0, 0, 0);
      acc[3][0][e] = __builtin_amdgcn_mfma_f32_16x16x32_bf16(A3, B0, acc[3][0][e], 0, 0, 0);
      acc[0][1][e] = __builtin_amdgcn_mfma_f32_16x16x32_bf16(A0, B1, acc[0][1][e], 0, 0, 0);
      acc[1][1][e] = __builtin_amdgcn_mfma_f32_16x16x32_bf16(A1, B1, acc[1][1][e], 0, 0, 0);
      acc[2][1][e] = __builtin_amdgcn_mfma_f32_16x16x32_bf16(A2, B1, acc[2][1][e], 0, 0, 0);
      acc[3][1][e] = __builtin_amdgcn_mfma_f32_16x16x32_bf16(A3, B1, acc[3][1][e], 0, 0, 0);
      if (we == e) {                         // A16 dedup: A16 == A[g]
        if (g == 0)      acc16 = __builtin_amdgcn_mfma_f32_16x16x32_bf16(A0, B16, acc16, 0, 0, 0);
        else if (g == 1) acc16 = __builtin_amdgcn_mfma_f32_16x16x32_bf16(A1, B16, acc16, 0, 0, 0);
        else if (g == 2) acc16 = __builtin_amdgcn_mfma_f32_16x16x32_bf16(A2, B16, acc16, 0, 0, 0);
        else             acc16 = __builtin_amdgcn_mfma_f32_16x16x32_bf16(A3, B16, acc16, 0, 0, 0);
      }
    }
  }
  __syncthreads();

  // ---- phase 2b: ks 4..7 from hldsB ----
#pragma unroll
  for (int ks = 0; ks < 4; ++ks) {
    sh8 B0  = *(const sh8*)(w2f + (((ks + 4) * 17 + t0)     * 64 + lane) * 8);
    sh8 B1  = *(const sh8*)(w2f + (((ks + 4) * 17 + t0 + 1) * 64 + lane) * 8);
    sh8 B16 = *(const sh8*)(w2f + (((ks + 4) * 17 + 16)     * 64 + lane) * 8);
#pragma unroll
    for (int e = 0; e < 2; ++e) {
      sh8 A0 = *(const sh8*)(&hldsB[e][((0 * 4 + ks) * 64 + lane) * 8]);
      sh8 A1 = *(const sh8*)(&hldsB[e][((1 * 4 + ks) * 64 + lane) * 8]);
      sh8 A2 = *(const sh8*)(&hldsB[e][((2 * 4 + ks) * 64 + lane) * 8]);
      sh8 A3 = *(const sh8*)(&hldsB[e][((3 * 4 + ks) * 64 + lane) * 8]);
      acc[0][0][e] = __builtin_amdgcn_mfma_f32_16x16x32_bf16(A0, B0, acc[0][0][e], 0, 0, 0);
      acc[1][0][e] = __builtin_amdgcn_mfma_f32_16x16x32_bf16(A1, B0, acc[1][0][e], 0, 0, 0);
      acc[2][0][e] = __builtin_amdgcn_mfma_f32_16x16x32_bf16(A2, B0, acc[2][0][e], 0, 0, 0);
      acc[3][0][e] = __builtin_amdgcn_mfma_f32_16x16x32_bf16(A3, B0, acc[3][0][e], 0, 0, 0);
      acc[0][1][e] = __builtin_amdgcn_mfma_f32_16x16x32_bf16(A0, B1, acc[0][1][e], 0, 0, 0);
      acc[1][1][e] = __builtin_amdgcn_mfma_f32_16x16x32_bf16(A1, B1, acc[1][1][e], 0, 0, 0);
      acc[2][1][e] = __builtin_amdgcn_mfma_f32_16x16x32_bf16(A2, B1, acc[2][1][e], 0, 0, 0);
      acc[3][1][e] = __builtin_amdgcn_mfma_f32_16x16x32_bf16(A3, B1, acc[3][1][e], 0, 0, 0);
      if (we == e) {                         // A16 dedup: A16 == A[g]
        if (g == 0)      acc16 = __builtin_amdgcn_mfma_f32_16x16x32_bf16(A0, B16, acc16, 0, 0, 0);
        else if (g == 1) acc16 = __builtin_amdgcn_mfma_f32_16x16x32_bf16(A1, B16, acc16, 0, 0, 0);
        else if (g == 2) acc16 = __builtin_amdgcn_mfma_f32_16x16x32_bf16(A2, B16, acc16, 0, 0, 0);
        else             acc16 = __builtin_amdgcn_mfma_f32_16x16x32_bf16(A3, B16, acc16, 0, 0, 0);
      }
    }
  }

  // ---- phase 3: relu + masked pool (bias already in acc via C-init) ----
  const float ninv[2] = {ninvp[0] + ninvp[1] + ninvp[2] + ninvp[3],
                         ninvp[4] + ninvp[5] + ninvp[6] + ninvp[7]};
#pragma unroll
  for (int i = 0; i < 2; ++i) {
    const int col = (t0 + i) * 16 + m;       // 0..255, always < EOUT
    const float bic = (i == 0) ? bi0 : bi1;
    const float rb2 = fmaxf(bic, 0.f);
#pragma unroll
    for (int e = 0; e < 2; ++e) {
      float ssum = 0.f;
#pragma unroll
      for (int mtA = 0; mtA < 4; ++mtA)
#pragma unroll
        for (int r = 0; r < 4; ++r)
          ssum += fmaxf(acc[mtA][i][e][r], 0.f);
      ssum += __shfl_xor(ssum, 16, 64);
      ssum += __shfl_xor(ssum, 32, 64);
      ssum -= ninv[e] * rb2;                 // invalid agents contribute relu(b2)
      if (q == 0) {
        size_t rr = bg0 + e; if (rr >= (size_t)B) rr = B - 1;
        so288[rr * XPAD + CAR + col] = ssum;
      }
    }
  }
  // tile 16 (cols 256..271): per-wave partial (16 agents of elem we)
  {
    float s16 = 0.f;
#pragma unroll
    for (int r = 0; r < 4; ++r)
      s16 += fmaxf(acc16[r], 0.f);
    s16 += __shfl_xor(s16, 16, 64);
    s16 += __shfl_xor(s16, 32, 64);
    if (q == 0) t16[w][m] = s16;
  }
  __syncthreads();
  if ((w == 0 || w == 4) && q == 0) {        // wave 0 -> elem 0, wave 4 -> elem 1
    const int e2 = w >> 2;
    const float b2c = (m == 0) ? b2[256] : 0.f;
    const float tot = t16[e2 * 4 + 0][m] + t16[e2 * 4 + 1][m] +
                      t16[e2 * 4 + 2][m] + t16[e2 * 4 + 3][m]
                    - ninv[e2] * fmaxf(b2c, 0.f);  // pad cols: all terms 0
    size_t rr2 = bg0 + e2; if (rr2 >= (size_t)B) rr2 = B - 1;
    so288[rr2 * XPAD + CAR + 256 + m] = tot;
  }
}

// ---------------------------------------------------------------------------
// K2: Q-head, MFMA. 4 waves, 16 batch rows per block (512 blocks -> 2/CU;
// verified R6, ~4 us better than 32-row).
// ---------------------------------------------------------------------------
__global__ __launch_bounds__(256, 2)
void k_q(const float* __restrict__ so288, const short* __restrict__ w3f,
         const float* __restrict__ Qb1, const short* __restrict__ wq2f,
         const float* __restrict__ Qb2, float* __restrict__ out, int B) {
  __shared__ __align__(16) short xf[9 * 64 * 8];  // 9.2 KB, [ks][lane][j]
  __shared__ __align__(16) float H[16 * 260];      // 16.6 KB
  const int tid = threadIdx.x;
  const int w = tid >> 6, lane = tid & 63;
  const int q = lane >> 4, m = lane & 15;
  const int b0 = blockIdx.x * 16;

  // ---- stage X (16 rows x 9 k-steps) ----
#pragma unroll
  for (int it = 0; it < 3; ++it) {
    int sidx = tid + it * 256;               // = ks*64 + l
    if (sidx < 576) {
      int ks = sidx >> 6, l = sidx & 63;
      int lq = l >> 4, lm = l & 15;
      int row = b0 + lm; if (row >= B) row = B - 1;
      const float* xp = so288 + (size_t)row * XPAD + ks * 32 + lq * 8;
      float4 xa = ((const float4*)xp)[0], xb = ((const float4*)xp)[1];
      int4 t = {(int)f2bf2(xa.x, xa.y), (int)f2bf2(xa.z, xa.w),
                (int)f2bf2(xb.x, xb.y), (int)f2bf2(xb.z, xb.w)};
      *(int4*)(xf + sidx * 8) = t;
    }
  }
  __syncthreads();

  // ---- GEMM1: X(16x288) @ Qw1 -> H ----
  f32x4 acc1[4];
#pragma unroll
  for (int i = 0; i < 4; ++i) {
    f32x4 z = {0.f, 0.f, 0.f, 0.f};
    acc1[i] = z;
  }
#pragma unroll
  for (int ks = 0; ks < 9; ++ks) {
    sh8 A0 = *(const sh8*)(xf + (ks * 64 + lane) * 8);
#pragma unroll
    for (int i = 0; i < 4; ++i) {
      sh8 Bf = *(const sh8*)(w3f + ((ks * 16 + 4 * w + i) * 64 + lane) * 8);
      acc1[i] = __builtin_amdgcn_mfma_f32_16x16x32_bf16(A0, Bf, acc1[i], 0, 0, 0);
    }
  }
#pragma unroll
  for (int i = 0; i < 4; ++i) {
    const int hcol = (4 * w + i) * 16 + m;
    const float bq = Qb1[hcol];
#pragma unroll
    for (int r = 0; r < 4; ++r)
      H[(q * 4 + r) * 260 + hcol] = fmaxf(acc1[i][r] + bq, 0.f);
  }
  __syncthreads();

  // ---- GEMM2: H(16x256) @ Qw2 -> out (waves 0,1) ----
  if (w < 2) {
    f32x4 acc2 = {0.f, 0.f, 0.f, 0.f};
#pragma unroll
    for (int ks = 0; ks < 8; ++ks) {
      const float* hp = H + m * 260 + ks * 32 + q * 8;
      float4 ha = ((const float4*)hp)[0], hb = ((const float4*)hp)[1];
      int4 t = {(int)f2bf2(ha.x, ha.y), (int)f2bf2(ha.z, ha.w),
                (int)f2bf2(hb.x, hb.y), (int)f2bf2(hb.z, hb.w)};
      sh8 A2 = __builtin_bit_cast(sh8, t);
      sh8 Bf = *(const sh8*)(wq2f + ((ks * 2 + w) * 64 + lane) * 8);
      acc2 = __builtin_amdgcn_mfma_f32_16x16x32_bf16(A2, Bf, acc2, 0, 0, 0);
    }
    const int act = w * 16 + m;
    if (act < ADIM) {
      const float bq = Qb2[act];
#pragma unroll
      for (int r = 0; r < 4; ++r) {
        const int row = b0 + q * 4 + r;
        if (row < B) out[(size_t)row * ADIM + act] = acc2[r] + bq;
      }
    }
  }
}

extern "C" void kernel_launch(void* const* d_in, const int* in_sizes, int n_in,
                              void* d_out, int out_size, void* d_ws, size_t ws_size,
                              hipStream_t stream) {
  const float* s   = (const float*)d_in[0];
  const float* W1  = (const float*)d_in[1];
  const float* b1  = (const float*)d_in[2];
  const float* W2  = (const float*)d_in[3];
  const float* b2  = (const float*)d_in[4];
  const float* Qw1 = (const float*)d_in[5];
  const float* Qb1 = (const float*)d_in[6];
  const float* Qw2 = (const float*)d_in[7];
  const float* Qb2 = (const float*)d_in[8];
  float* out = (float*)d_out;
  const int B = in_sizes[0] / SROW;

  // ws: [so288: B*288 f32][w1f 8192][w2f 69632][w3f 73728][wq2f 8192] bf16
  char* wsb = (char*)d_ws;
  float* so288 = (float*)wsb;
  size_t off = (size_t)B * XPAD * sizeof(float);
  short* w1f  = (short*)(wsb + off);            off += 8192 * 2;
  short* w2f  = (short*)(wsb + off);            off += 69632 * 2;
  short* w3f  = (short*)(wsb + off);            off += 73728 * 2;
  short* wq2f = (short*)(wsb + off);

  const int prep_elems = 8192 + 69632 + 73728 + 8192;
  k_prep<<<(prep_elems + 255) / 256, 256, 0, stream>>>(W1, b1, W2, Qw1, Qw2,
                                                       w1f, w2f, w3f, wq2f);
  k_enc<<<(B + 1) / 2, 512, 0, stream>>>(s, w1f, w2f, b2, so288, B);
  k_q<<<(B + 15) / 16, 256, 0, stream>>>(so288, w3f, Qb1, wq2f, Qb2, out, B);
}

// Round 8
// 163.231 us; speedup vs baseline: 1.0565x; 1.0565x over previous
//
#include <hip/hip_runtime.h>

#define CAR 8
#define SROW 520   // CAR + 64*CAR
#define HID 256
#define EOUT 257
#define XPAD 288   // padded Q-input row: 8 self + 257 enc + pad, 9 k-steps of 32
#define ADIM 30

typedef __attribute__((ext_vector_type(8))) short sh8;
typedef __attribute__((ext_vector_type(4))) float f32x4;

__device__ __forceinline__ short f2bf(float f) {
  unsigned u = __builtin_bit_cast(unsigned, f);
  u += 0x7fffu + ((u >> 16) & 1u);   // RNE
  return (short)(u >> 16);
}
// pack two fp32 -> packed bf16x2 (RNE, 5 VALU)
__device__ __forceinline__ unsigned f2bf2(float a, float b) {
  unsigned ua = __builtin_bit_cast(unsigned, a);
  ua += 0x7fffu + ((ua >> 16) & 1u);
  unsigned ub = __builtin_bit_cast(unsigned, b);
  ub += 0x7fffu + ((ub >> 16) & 1u);
  return __builtin_amdgcn_perm(ub, ua, 0x07060302);  // [a | b<<16]
}
// pack two fp32 -> packed bf16x2 (TRUNC, 1 VALU) — used for h staging only
__device__ __forceinline__ unsigned pkt(float a, float b) {
  return __builtin_amdgcn_perm(__builtin_bit_cast(unsigned, b),
                               __builtin_bit_cast(unsigned, a), 0x07060302);
}

// ---------------------------------------------------------------------------
// Prep: swizzle all weights to bf16 MFMA fragments. (R2-verbatim, verified)
// w1f : [W1;b1]^T as A [16 mt][64][8]  k=0..7 -> W1 row, k=8 -> b1   (8192)
// w2f : W2  as B   [8 ks][17 nt][64][8]               (69632)  stride/ks = 8704!
// w3f : Qw1 as B   [9 ks][16 nt][64][8], k=X-row idx  (73728)
// wq2f: Qw2 as B   [8 ks][2 nt][64][8]                (8192)
// ---------------------------------------------------------------------------
__global__ void k_prep(const float* __restrict__ W1, const float* __restrict__ b1,
                       const float* __restrict__ W2,
                       const float* __restrict__ Qw1, const float* __restrict__ Qw2,
                       short* __restrict__ w1f, short* __restrict__ w2f,
                       short* __restrict__ w3f, short* __restrict__ wq2f) {
  int idx = blockIdx.x * 256 + threadIdx.x;
  if (idx < 8192) {                         // [W1;b1]^T as A
    int mt = idx >> 9, r = idx & 511, lane = r >> 3, j = r & 7;
    int quad = lane >> 4, m = lane & 15;
    int hid = mt * 16 + m;
    float v = (quad == 0) ? W1[j * HID + hid]
            : (quad == 1 && j == 0) ? b1[hid] : 0.0f;   // k=8 row = b1
    w1f[idx] = f2bf(v);
    return;
  }
  int i2 = idx - 8192;
  if (i2 < 69632) {                         // W2 as B (ks stride = 17*512 = 8704)
    int ks = i2 / 8704, r = i2 % 8704;
    int nt = r >> 9, r2 = r & 511, lane = r2 >> 3, j = r2 & 7;
    int quad = lane >> 4, m = lane & 15;
    int k = ks * 32 + quad * 8 + j, n = nt * 16 + m;
    float v = (n < EOUT) ? W2[k * EOUT + n] : 0.0f;
    w2f[i2] = f2bf(v);
    return;
  }
  int i3 = i2 - 69632;
  if (i3 < 73728) {                         // Qw1 as B (k indexes padded X row)
    int ks = i3 >> 13, r = i3 & 8191;
    int nt = r >> 9, r2 = r & 511, lane = r2 >> 3, j = r2 & 7;
    int quad = lane >> 4, m = lane & 15;
    int k = ks * 32 + quad * 8 + j, n = nt * 16 + m;
    float v = (k < 265) ? Qw1[k * HID + n] : 0.0f;
    w3f[i3] = f2bf(v);
    return;
  }
  int i4 = i3 - 73728;
  if (i4 < 8192) {                          // Qw2 as B
    int ks = i4 >> 10, r = i4 & 1023;
    int nt = r >> 9, r2 = r & 511, lane = r2 >> 3, j = r2 & 7;
    int quad = lane >> 4, m = lane & 15;
    int k = ks * 32 + quad * 8 + j, n = nt * 16 + m;
    float v = (n < ADIM) ? Qw2[k * ADIM + n] : 0.0f;
    wq2f[i4] = f2bf(v);
  }
}

// ---------------------------------------------------------------------------
// K1: fused encoder + pool. NB=2 elems, 8 waves (512 thr). R2-verified base +
// (a) A16-dedup (verified): acc16 reuses A[g] instead of a 9th ds_read.
// (b) bias-as-C-init (verified): acc starts at b2[col]; removes 68 epilogue
//     v_adds; math identical.
// NO setprio (R6: −6 us regression, SALU pollution of the hot loop).
// NO K-split pipeline (R7: scratch spill, WRITE_SIZE 11->92 MB).
// Wave w: elem we=w>>2, agent group g=w&3; phase 2 tiles {2w, 2w+1}.
// ---------------------------------------------------------------------------
__global__ __launch_bounds__(512, 4)
void k_enc(const float* __restrict__ s, const short* __restrict__ w1f,
           const short* __restrict__ w2f, const float* __restrict__ b2,
           float* __restrict__ so288, int B) {
  __shared__ __align__(16) short hlds[2][16384];  // 64 KB: [e][(g*8+ks)*64+slot]*8+j
  __shared__ float ninvp[8];
  __shared__ float t16[8][16];

  const int tid = threadIdx.x;
  const int w = tid >> 6, lane = tid & 63;
  const int q = lane >> 4, m = lane & 15;
  const int we = w >> 2, g = w & 3;
  const size_t bg0 = 2 * (size_t)blockIdx.x;
  size_t bg = bg0 + we; if (bg >= (size_t)B) bg = B - 1;

  // ---- phase 1: h = relu([surr,1]@[W1;b1]) for 16 agents (g) of elem we ----
  const float* srow0 = s + bg * SROW + CAR;
  int4 pk = {0, 0, 0, 0};
  bool inv = false;
  if (lane < 16) {                           // agent = 16*g + lane
    const float* sr = srow0 + (g * 16 + lane) * CAR;
    float4 f0 = ((const float4*)sr)[0], f1 = ((const float4*)sr)[1];
    inv = (f0.x == -1.f) | (f0.y == -1.f) | (f0.z == -1.f) | (f0.w == -1.f) |
          (f1.x == -1.f) | (f1.y == -1.f) | (f1.z == -1.f) | (f1.w == -1.f);
    if (!inv) {                              // mask folded at source
      pk.x = (int)f2bf2(f0.x, f0.y); pk.y = (int)f2bf2(f0.z, f0.w);
      pk.z = (int)f2bf2(f1.x, f1.y); pk.w = (int)f2bf2(f1.z, f1.w);
    }
  }
  const float vflag = inv ? 0.f : 1.f;
  unsigned long long bal = __ballot(inv);
  if (lane == 0) ninvp[w] = (float)__popcll(bal);

  if (w == 1 || w == 2) {                    // self-state + tail pad per elem
    size_t rr = bg0 + (w - 1); if (rr >= (size_t)B) rr = B - 1;
    if (lane < CAR)       so288[rr * XPAD + lane] = s[rr * SROW + lane];
    else if (lane < 16)   so288[rr * XPAD + 280 + (lane - 8)] = 0.f;
  }

  int4 p0;
  p0.x = __shfl(pk.x, m, 64); p0.y = __shfl(pk.y, m, 64);
  p0.z = __shfl(pk.z, m, 64); p0.w = __shfl(pk.w, m, 64);
  const float vv0 = __shfl(vflag, m, 64);
  if (q == 1) {                              // k=8 constant-1 column (masked)
    p0.x = (vv0 != 0.f) ? 0x3f80 : 0; p0.y = p0.z = p0.w = 0;
  } else if (q >= 2) {
    p0.x = p0.y = p0.z = p0.w = 0;
  }
  sh8 bs = __builtin_bit_cast(sh8, p0);

#pragma unroll 4
  for (int mt = 0; mt < 16; ++mt) {
    sh8 af = *(const sh8*)(w1f + (mt * 64 + lane) * 8);
    f32x4 z = {0.f, 0.f, 0.f, 0.f};
    f32x4 c0 = __builtin_amdgcn_mfma_f32_16x16x32_bf16(af, bs, z, 0, 0, 0);
    const int hidb = mt * 16 + q * 4;
    const int ks = hidb >> 5, qB = (hidb >> 3) & 3, js = hidb & 7;
    uint2 k0;
    k0.x = pkt(fmaxf(c0[0], 0.f), fmaxf(c0[1], 0.f));
    k0.y = pkt(fmaxf(c0[2], 0.f), fmaxf(c0[3], 0.f));
    *(uint2*)(&hlds[we][((g * 8 + ks) * 64 + qB * 16 + m) * 8 + js]) = k0;
  }
  __syncthreads();

  // ---- phase 2: enc = h @ W2, tiles {2w, 2w+1} both elems + dedup'd tile16 -
  const int t0 = 2 * w;
  const float bi0  = b2[t0 * 16 + m];        // bias as C-init (col-indexed)
  const float bi1  = b2[t0 * 16 + 16 + m];
  const float bi16 = (m == 0) ? b2[256] : 0.f;
  f32x4 acc[4][2][2];                        // [mtA][i][e]
  f32x4 acc16 = {bi16, bi16, bi16, bi16};
#pragma unroll
  for (int mtA = 0; mtA < 4; ++mtA)
#pragma unroll
    for (int e = 0; e < 2; ++e) {
      f32x4 c0 = {bi0, bi0, bi0, bi0};
      f32x4 c1 = {bi1, bi1, bi1, bi1};
      acc[mtA][0][e] = c0;
      acc[mtA][1][e] = c1;
    }
#pragma unroll
  for (int ks = 0; ks < 8; ++ks) {
    sh8 B0  = *(const sh8*)(w2f + ((ks * 17 + t0)     * 64 + lane) * 8);
    sh8 B1  = *(const sh8*)(w2f + ((ks * 17 + t0 + 1) * 64 + lane) * 8);
    sh8 B16 = *(const sh8*)(w2f + ((ks * 17 + 16)     * 64 + lane) * 8);
#pragma unroll
    for (int e = 0; e < 2; ++e) {
      sh8 A0 = *(const sh8*)(&hlds[e][(0 * 8 + ks) * 512 + lane * 8]);
      sh8 A1 = *(const sh8*)(&hlds[e][(1 * 8 + ks) * 512 + lane * 8]);
      sh8 A2 = *(const sh8*)(&hlds[e][(2 * 8 + ks) * 512 + lane * 8]);
      sh8 A3 = *(const sh8*)(&hlds[e][(3 * 8 + ks) * 512 + lane * 8]);
      acc[0][0][e] = __builtin_amdgcn_mfma_f32_16x16x32_bf16(A0, B0, acc[0][0][e], 0, 0, 0);
      acc[1][0][e] = __builtin_amdgcn_mfma_f32_16x16x32_bf16(A1, B0, acc[1][0][e], 0, 0, 0);
      acc[2][0][e] = __builtin_amdgcn_mfma_f32_16x16x32_bf16(A2, B0, acc[2][0][e], 0, 0, 0);
      acc[3][0][e] = __builtin_amdgcn_mfma_f32_16x16x32_bf16(A3, B0, acc[3][0][e], 0, 0, 0);
      acc[0][1][e] = __builtin_amdgcn_mfma_f32_16x16x32_bf16(A0, B1, acc[0][1][e], 0, 0, 0);
      acc[1][1][e] = __builtin_amdgcn_mfma_f32_16x16x32_bf16(A1, B1, acc[1][1][e], 0, 0, 0);
      acc[2][1][e] = __builtin_amdgcn_mfma_f32_16x16x32_bf16(A2, B1, acc[2][1][e], 0, 0, 0);
      acc[3][1][e] = __builtin_amdgcn_mfma_f32_16x16x32_bf16(A3, B1, acc[3][1][e], 0, 0, 0);
      if (we == e) {                         // A16 dedup: A16 == A[g]
        if (g == 0)      acc16 = __builtin_amdgcn_mfma_f32_16x16x32_bf16(A0, B16, acc16, 0, 0, 0);
        else if (g == 1) acc16 = __builtin_amdgcn_mfma_f32_16x16x32_bf16(A1, B16, acc16, 0, 0, 0);
        else if (g == 2) acc16 = __builtin_amdgcn_mfma_f32_16x16x32_bf16(A2, B16, acc16, 0, 0, 0);
        else             acc16 = __builtin_amdgcn_mfma_f32_16x16x32_bf16(A3, B16, acc16, 0, 0, 0);
      }
    }
  }

  // ---- phase 3: relu + masked pool (bias already in acc via C-init) ----
  const float ninv[2] = {ninvp[0] + ninvp[1] + ninvp[2] + ninvp[3],
                         ninvp[4] + ninvp[5] + ninvp[6] + ninvp[7]};
#pragma unroll
  for (int i = 0; i < 2; ++i) {
    const int col = (t0 + i) * 16 + m;       // 0..255, always < EOUT
    const float bic = (i == 0) ? bi0 : bi1;
    const float rb2 = fmaxf(bic, 0.f);
#pragma unroll
    for (int e = 0; e < 2; ++e) {
      float ssum = 0.f;
#pragma unroll
      for (int mtA = 0; mtA < 4; ++mtA)
#pragma unroll
        for (int r = 0; r < 4; ++r)
          ssum += fmaxf(acc[mtA][i][e][r], 0.f);
      ssum += __shfl_xor(ssum, 16, 64);
      ssum += __shfl_xor(ssum, 32, 64);
      ssum -= ninv[e] * rb2;                 // invalid agents contribute relu(b2)
      if (q == 0) {
        size_t rr = bg0 + e; if (rr >= (size_t)B) rr = B - 1;
        so288[rr * XPAD + CAR + col] = ssum;
      }
    }
  }
  // tile 16 (cols 256..271): per-wave partial (16 agents of elem we)
  {
    float s16 = 0.f;
#pragma unroll
    for (int r = 0; r < 4; ++r)
      s16 += fmaxf(acc16[r], 0.f);
    s16 += __shfl_xor(s16, 16, 64);
    s16 += __shfl_xor(s16, 32, 64);
    if (q == 0) t16[w][m] = s16;
  }
  __syncthreads();
  if ((w == 0 || w == 4) && q == 0) {        // wave 0 -> elem 0, wave 4 -> elem 1
    const int e2 = w >> 2;
    const float b2c = (m == 0) ? b2[256] : 0.f;
    const float tot = t16[e2 * 4 + 0][m] + t16[e2 * 4 + 1][m] +
                      t16[e2 * 4 + 2][m] + t16[e2 * 4 + 3][m]
                    - ninv[e2] * fmaxf(b2c, 0.f);  // pad cols: all terms 0
    size_t rr2 = bg0 + e2; if (rr2 >= (size_t)B) rr2 = B - 1;
    so288[rr2 * XPAD + CAR + 256 + m] = tot;
  }
}

// ---------------------------------------------------------------------------
// K2: Q-head, MFMA. 4 waves, 16 batch rows per block (512 blocks -> 2/CU;
// verified R6, ~4 us better than 32-row).
// ---------------------------------------------------------------------------
__global__ __launch_bounds__(256, 2)
void k_q(const float* __restrict__ so288, const short* __restrict__ w3f,
         const float* __restrict__ Qb1, const short* __restrict__ wq2f,
         const float* __restrict__ Qb2, float* __restrict__ out, int B) {
  __shared__ __align__(16) short xf[9 * 64 * 8];  // 9.2 KB, [ks][lane][j]
  __shared__ __align__(16) float H[16 * 260];      // 16.6 KB
  const int tid = threadIdx.x;
  const int w = tid >> 6, lane = tid & 63;
  const int q = lane >> 4, m = lane & 15;
  const int b0 = blockIdx.x * 16;

  // ---- stage X (16 rows x 9 k-steps) ----
#pragma unroll
  for (int it = 0; it < 3; ++it) {
    int sidx = tid + it * 256;               // = ks*64 + l
    if (sidx < 576) {
      int ks = sidx >> 6, l = sidx & 63;
      int lq = l >> 4, lm = l & 15;
      int row = b0 + lm; if (row >= B) row = B - 1;
      const float* xp = so288 + (size_t)row * XPAD + ks * 32 + lq * 8;
      float4 xa = ((const float4*)xp)[0], xb = ((const float4*)xp)[1];
      int4 t = {(int)f2bf2(xa.x, xa.y), (int)f2bf2(xa.z, xa.w),
                (int)f2bf2(xb.x, xb.y), (int)f2bf2(xb.z, xb.w)};
      *(int4*)(xf + sidx * 8) = t;
    }
  }
  __syncthreads();

  // ---- GEMM1: X(16x288) @ Qw1 -> H ----
  f32x4 acc1[4];
#pragma unroll
  for (int i = 0; i < 4; ++i) {
    f32x4 z = {0.f, 0.f, 0.f, 0.f};
    acc1[i] = z;
  }
#pragma unroll
  for (int ks = 0; ks < 9; ++ks) {
    sh8 A0 = *(const sh8*)(xf + (ks * 64 + lane) * 8);
#pragma unroll
    for (int i = 0; i < 4; ++i) {
      sh8 Bf = *(const sh8*)(w3f + ((ks * 16 + 4 * w + i) * 64 + lane) * 8);
      acc1[i] = __builtin_amdgcn_mfma_f32_16x16x32_bf16(A0, Bf, acc1[i], 0, 0, 0);
    }
  }
#pragma unroll
  for (int i = 0; i < 4; ++i) {
    const int hcol = (4 * w + i) * 16 + m;
    const float bq = Qb1[hcol];
#pragma unroll
    for (int r = 0; r < 4; ++r)
      H[(q * 4 + r) * 260 + hcol] = fmaxf(acc1[i][r] + bq, 0.f);
  }
  __syncthreads();

  // ---- GEMM2: H(16x256) @ Qw2 -> out (waves 0,1) ----
  if (w < 2) {
    f32x4 acc2 = {0.f, 0.f, 0.f, 0.f};
#pragma unroll
    for (int ks = 0; ks < 8; ++ks) {
      const float* hp = H + m * 260 + ks * 32 + q * 8;
      float4 ha = ((const float4*)hp)[0], hb = ((const float4*)hp)[1];
      int4 t = {(int)f2bf2(ha.x, ha.y), (int)f2bf2(ha.z, ha.w),
                (int)f2bf2(hb.x, hb.y), (int)f2bf2(hb.z, hb.w)};
      sh8 A2 = __builtin_bit_cast(sh8, t);
      sh8 Bf = *(const sh8*)(wq2f + ((ks * 2 + w) * 64 + lane) * 8);
      acc2 = __builtin_amdgcn_mfma_f32_16x16x32_bf16(A2, Bf, acc2, 0, 0, 0);
    }
    const int act = w * 16 + m;
    if (act < ADIM) {
      const float bq = Qb2[act];
#pragma unroll
      for (int r = 0; r < 4; ++r) {
        const int row = b0 + q * 4 + r;
        if (row < B) out[(size_t)row * ADIM + act] = acc2[r] + bq;
      }
    }
  }
}

extern "C" void kernel_launch(void* const* d_in, const int* in_sizes, int n_in,
                              void* d_out, int out_size, void* d_ws, size_t ws_size,
                              hipStream_t stream) {
  const float* s   = (const float*)d_in[0];
  const float* W1  = (const float*)d_in[1];
  const float* b1  = (const float*)d_in[2];
  const float* W2  = (const float*)d_in[3];
  const float* b2  = (const float*)d_in[4];
  const float* Qw1 = (const float*)d_in[5];
  const float* Qb1 = (const float*)d_in[6];
  const float* Qw2 = (const float*)d_in[7];
  const float* Qb2 = (const float*)d_in[8];
  float* out = (float*)d_out;
  const int B = in_sizes[0] / SROW;

  // ws: [so288: B*288 f32][w1f 8192][w2f 69632][w3f 73728][wq2f 8192] bf16
  char* wsb = (char*)d_ws;
  float* so288 = (float*)wsb;
  size_t off = (size_t)B * XPAD * sizeof(float);
  short* w1f  = (short*)(wsb + off);            off += 8192 * 2;
  short* w2f  = (short*)(wsb + off);            off += 69632 * 2;
  short* w3f  = (short*)(wsb + off);            off += 73728 * 2;
  short* wq2f = (short*)(wsb + off);

  const int prep_elems = 8192 + 69632 + 73728 + 8192;
  k_prep<<<(prep_elems + 255) / 256, 256, 0, stream>>>(W1, b1, W2, Qw1, Qw2,
                                                       w1f, w2f, w3f, wq2f);
  k_enc<<<(B + 1) / 2, 512, 0, stream>>>(s, w1f, w2f, b2, so288, B);
  k_q<<<(B + 15) / 16, 256, 0, stream>>>(so288, w3f, Qb1, wq2f, Qb2, out, B);
}